// Round 17
// baseline (256.721 us; speedup 1.0000x reference)
//
#include <hip/hip_runtime.h>

// relationalGraphStack — round 16
// vs R14 (239.4 record; R15's atomic-MLP reverted — count is RMW-throughput
// bound): layer 1 switched to gatherx -> K=576 MFMA GEMM (R9 numerics):
//  - k_countx: count (R14 structure) + xb convert fused (gemm1 gone from it).
//  - k_gatherx: gathers xb (6.4MB, L2-resident) per (node,r) with inline-d,
//    writes updx[N][512] bf16 COALESCED into d_out (~51MB seq vs 51MB random).
//  - k_gemm1b: [updx|xb] @ wb1^T, K=576, layer-1 column stats fused in epilogue.
//  - s1 / y1 slabs / separate stats pass eliminated.

#define GATHER_GRID 2048
#define SCAN_CHUNK 4096
#define RED_BLOCKS 64
#define ZERO_BLOCKS 256
#define PACK_BLOCKS 16
#define XB_BLOCKS 64
#define COUNT_BLOCKS 2048
#define PLACE_BLOCKS 1024

typedef short bf16x8 __attribute__((ext_vector_type(8)));
typedef float f32x4 __attribute__((ext_vector_type(4)));

static __device__ __forceinline__ float bf2f(unsigned short u) {
  return __uint_as_float(((unsigned)u) << 16);
}
static __device__ __forceinline__ unsigned short f2bf(float f) {
  unsigned u = __float_as_uint(f);
  u += 0x7FFFu + ((u >> 16) & 1u);  // round to nearest even
  return (unsigned short)(u >> 16);
}

// zero cnt + pack weights. wb1[j*576+k]: k<512 -> W_lin1[j*512+k], else W_self1[j][k-512].
// wb2[(s*64+j)*64+d]: s=0 W_lin2, s=1 W_self2.
__global__ void k_zeropack(int* __restrict__ cnt, int NR, int R,
                           const float* __restrict__ Wlin1, const float* __restrict__ Wself1,
                           const float* __restrict__ Wlin2, const float* __restrict__ Wself2,
                           unsigned short* __restrict__ wb1, unsigned short* __restrict__ wb2) {
  if (blockIdx.x < ZERO_BLOCKS) {
    int i = blockIdx.x * 256 + threadIdx.x;
    int stride = ZERO_BLOCKS * 256;
    for (int k = i; k < NR; k += stride) cnt[k] = 0;
  } else {
    int i = (blockIdx.x - ZERO_BLOCKS) * 256 + threadIdx.x;
    int stride = PACK_BLOCKS * 256;
    int KW = R * 64 + 64;                 // 576
    int n1 = 64 * KW;
    int n2 = 2 * 64 * 64;
    for (int t = i; t < n1 + n2; t += stride) {
      if (t < n1) {
        int j = t / KW, k = t - j * KW;
        float v = (k < R * 64) ? Wlin1[j * (R * 64) + k] : Wself1[j * 64 + (k - R * 64)];
        wb1[t] = f2bf(v);
      } else {
        int t2 = t - n1;
        int r = t2 >> 6, d = t2 & 63;
        float v = (r < 64) ? Wlin2[r * 64 + d] : Wself2[(r - 64) * 64 + d];
        wb2[t2] = f2bf(v);
      }
    }
  }
}

// blocks [0,XB_BLOCKS): x f32 -> xb bf16.  blocks [XB_BLOCKS,...): count + rank.
__global__ void k_countx(const int* __restrict__ node_out, const int* __restrict__ rel,
                         int* __restrict__ cnt, int* __restrict__ tmp, int E, int R,
                         const float4* __restrict__ xin, ushort4* __restrict__ xb, int n4) {
  if (blockIdx.x < XB_BLOCKS) {
    int i = blockIdx.x * 256 + threadIdx.x;
    int stride = XB_BLOCKS * 256;
    for (int k = i; k < n4; k += stride) {
      float4 v = xin[k];
      ushort4 o;
      o.x = f2bf(v.x); o.y = f2bf(v.y); o.z = f2bf(v.z); o.w = f2bf(v.w);
      xb[k] = o;
    }
  } else {
    int i = (blockIdx.x - XB_BLOCKS) * 256 + threadIdx.x;
    int stride = COUNT_BLOCKS * 256;
    for (int e = i; e < E; e += stride) {
      int seg = node_out[e] * R + rel[e];
      tmp[e] = atomicAdd(&cnt[seg], 1);
    }
  }
}

__global__ __launch_bounds__(256) void k_scan1(const int* __restrict__ cnt,
                                               int* __restrict__ bsum, int NR) {
  __shared__ int red[256];
  int tid = threadIdx.x;
  int base = blockIdx.x * SCAN_CHUNK;
  int s = 0;
  for (int i = tid; i < SCAN_CHUNK; i += 256) {
    int idx = base + i;
    if (idx < NR) s += cnt[idx];
  }
  red[tid] = s;
  __syncthreads();
  for (int off = 128; off > 0; off >>= 1) {
    if (tid < off) red[tid] += red[tid + off];
    __syncthreads();
  }
  if (tid == 0) bsum[blockIdx.x] = red[0];
}

__global__ void k_scan2(const int* __restrict__ bsum, int* __restrict__ bpre,
                        int* __restrict__ rowptr_end, int NB) {
  int lane = threadIdx.x;
  int carry = 0;
  for (int base = 0; base < NB; base += 64) {
    int i = base + lane;
    int v = (i < NB) ? bsum[i] : 0;
    int incl = v;
    #pragma unroll
    for (int off = 1; off < 64; off <<= 1) {
      int u = __shfl_up(incl, off);
      if (lane >= off) incl += u;
    }
    if (i < NB) bpre[i] = carry + incl - v;
    carry += __shfl(incl, 63);
  }
  if (lane == 0) *rowptr_end = carry;
}

// rowptr (n-major) + descT (s-major: descT[r*N+n] = start | cnt<<20)
__global__ __launch_bounds__(256) void k_scan3(const int* __restrict__ cnt,
                                               const int* __restrict__ bpre,
                                               int* __restrict__ rowptr,
                                               unsigned* __restrict__ descT,
                                               int NR, int R, int Nn) {
  __shared__ int wtot[4];
  int tid = threadIdx.x, lane = tid & 63, wid = tid >> 6;
  int base = blockIdx.x * SCAN_CHUNK + tid * 16;
  int v[16];
  int t = 0;
  #pragma unroll
  for (int i = 0; i < 16; i++) {
    int idx = base + i;
    v[i] = (idx < NR) ? cnt[idx] : 0;
    t += v[i];
  }
  int incl = t;
  #pragma unroll
  for (int off = 1; off < 64; off <<= 1) {
    int u = __shfl_up(incl, off);
    if (lane >= off) incl += u;
  }
  if (lane == 63) wtot[wid] = incl;
  __syncthreads();
  int woff = 0;
  for (int w = 0; w < wid; w++) woff += wtot[w];
  int start = bpre[blockIdx.x] + woff + incl - t;
  #pragma unroll
  for (int i = 0; i < 16; i++) {
    int idx = base + i;
    if (idx < NR) {
      rowptr[idx] = start;
      int n = (int)((unsigned)idx / (unsigned)R);
      int r = idx - n * R;
      descT[(size_t)r * Nn + n] = (unsigned)start | ((unsigned)v[i] << 20);
    }
    start += v[i];
  }
}

// placement, no atomics, 4B payload (R14 structure).
__global__ void k_place(const float* __restrict__ w, const int* __restrict__ node_out,
                        const int* __restrict__ node_in, const int* __restrict__ rel,
                        const int* __restrict__ rowptr, const int* __restrict__ tmp,
                        unsigned* __restrict__ ep4, int E, int R) {
  int i = blockIdx.x * blockDim.x + threadIdx.x;
  int stride = gridDim.x * blockDim.x;
  for (int e = i; e < E; e += stride) {
    int seg = node_out[e] * R + rel[e];
    int pos = rowptr[seg] + tmp[e];
    ep4[pos] = (unsigned)node_in[e] | ((unsigned)f2bf(w[e]) << 16);
  }
}

// gather x per (node, r) with inline-d: updx[n*512 + r*64 + c] (bf16, coalesced)
__global__ __launch_bounds__(256) void k_gatherx(
    const int* __restrict__ rowptr, const unsigned* __restrict__ ep4,
    const unsigned short* __restrict__ xb, unsigned short* __restrict__ updx,
    int N, int R) {
  int lane = threadIdx.x & 63;
  int wid = threadIdx.x >> 6;
  int l16 = lane & 15;
  int lg = lane >> 4;
  int c0 = l16 * 4;
  int grp = blockIdx.x * 16 + wid * 4 + lg;
  int ngrp = gridDim.x * 16;
  for (int n = grp; n < N; n += ngrp) {
    int segbase = n * R;
    int k = rowptr[segbase];
    for (int r = 0; r < R; r++) {
      int k1 = rowptr[segbase + r + 1];
      float a0 = 0.f, a1 = 0.f, a2 = 0.f, a3 = 0.f, d = 0.f;
      for (; k + 1 < k1; k += 2) {
        unsigned pA = ep4[k], pB = ep4[k + 1];
        ushort4 uA = *(const ushort4*)&xb[(size_t)(pA & 0xFFFFu) * 64 + c0];
        ushort4 uB = *(const ushort4*)&xb[(size_t)(pB & 0xFFFFu) * 64 + c0];
        float wA = bf2f((unsigned short)(pA >> 16));
        float wB = bf2f((unsigned short)(pB >> 16));
        d += wA + wB;
        a0 = fmaf(wA, bf2f(uA.x), a0); a1 = fmaf(wA, bf2f(uA.y), a1);
        a2 = fmaf(wA, bf2f(uA.z), a2); a3 = fmaf(wA, bf2f(uA.w), a3);
        a0 = fmaf(wB, bf2f(uB.x), a0); a1 = fmaf(wB, bf2f(uB.y), a1);
        a2 = fmaf(wB, bf2f(uB.z), a2); a3 = fmaf(wB, bf2f(uB.w), a3);
      }
      if (k < k1) {
        unsigned p = ep4[k];
        float w = bf2f((unsigned short)(p >> 16));
        ushort4 u = *(const ushort4*)&xb[(size_t)(p & 0xFFFFu) * 64 + c0];
        d += w;
        a0 = fmaf(w, bf2f(u.x), a0); a1 = fmaf(w, bf2f(u.y), a1);
        a2 = fmaf(w, bf2f(u.z), a2); a3 = fmaf(w, bf2f(u.w), a3);
        k = k1;
      }
      if (d != 0.f) {
        float inv = 1.f / d;
        a0 *= inv; a1 *= inv; a2 *= inv; a3 *= inv;
      }
      ushort4 o; o.x = f2bf(a0); o.y = f2bf(a1); o.z = f2bf(a2); o.w = f2bf(a3);
      *(ushort4*)&updx[(size_t)n * 512 + r * 64 + c0] = o;
    }
  }
}

// GEMM1b: h_pre[m,j] = sum_k [updx|xb][m,k] * wb1[j,k], K=576; bf16 out;
// layer-1 column stats fused in epilogue -> part[block][128].
__global__ __launch_bounds__(256) void k_gemm1b(
    const unsigned short* __restrict__ updx, const unsigned short* __restrict__ xb,
    int M, const unsigned short* __restrict__ wb1, unsigned short* __restrict__ h_pre,
    float* __restrict__ part) {
  int m0 = blockIdx.x * 64;
  int wid = threadIdx.x >> 6;
  int lane = threadIdx.x & 63;
  int mrow = m0 + wid * 16 + (lane & 15);
  int mload = (mrow < M) ? mrow : (M - 1);
  int koff = 8 * (lane >> 4);
  const unsigned short* aU = updx + (size_t)mload * 512 + koff;
  const unsigned short* aX = xb + (size_t)mload * 64 + koff;
  const unsigned short* wr = wb1 + (size_t)(lane & 15) * 576 + koff;
  f32x4 acc[4] = {{0,0,0,0},{0,0,0,0},{0,0,0,0},{0,0,0,0}};
  #pragma unroll
  for (int kk = 0; kk < 16; ++kk) {
    bf16x8 a = *(const bf16x8*)(aU + kk * 32);
    #pragma unroll
    for (int nt = 0; nt < 4; ++nt) {
      bf16x8 b = *(const bf16x8*)(wr + (size_t)nt * 16 * 576 + kk * 32);
      acc[nt] = __builtin_amdgcn_mfma_f32_16x16x32_bf16(a, b, acc[nt], 0, 0, 0);
    }
  }
  #pragma unroll
  for (int kk = 0; kk < 2; ++kk) {
    bf16x8 a = *(const bf16x8*)(aX + kk * 32);
    #pragma unroll
    for (int nt = 0; nt < 4; ++nt) {
      bf16x8 b = *(const bf16x8*)(wr + (size_t)nt * 16 * 576 + 512 + kk * 32);
      acc[nt] = __builtin_amdgcn_mfma_f32_16x16x32_bf16(a, b, acc[nt], 0, 0, 0);
    }
  }
  int rbase = m0 + wid * 16 + ((lane >> 4) << 2);
  int cbase = lane & 15;
  #pragma unroll
  for (int nt = 0; nt < 4; ++nt) {
    int col = nt * 16 + cbase;
    #pragma unroll
    for (int rg = 0; rg < 4; ++rg) {
      int grow = rbase + rg;
      if (grow < M) h_pre[(size_t)grow * 64 + col] = f2bf(acc[nt][rg]);
    }
  }
  // stats epilogue: column sums/sumsqs over this block's valid rows.
  __shared__ float sp[16][64], sq[16][64];
  int strip = wid * 4 + (lane >> 4);
  #pragma unroll
  for (int nt = 0; nt < 4; ++nt) {
    float cs = 0.f, cq = 0.f;
    #pragma unroll
    for (int rg = 0; rg < 4; ++rg) {
      int grow = rbase + rg;
      float v = (grow < M) ? acc[nt][rg] : 0.f;
      cs += v; cq += v * v;
    }
    int col = nt * 16 + cbase;
    sp[strip][col] = cs;
    sq[strip][col] = cq;
  }
  __syncthreads();
  if (threadIdx.x < 64) {
    int j = threadIdx.x;
    float s = 0.f, q = 0.f;
    #pragma unroll
    for (int g = 0; g < 16; g++) { s += sp[g][j]; q += sq[g][j]; }
    part[(size_t)blockIdx.x * 128 + j] = s;
    part[(size_t)blockIdx.x * 128 + 64 + j] = q;
  }
}

// gemm2 with fused bn+relu on A (h_pre) using ss1 -> z bf16, s2 bf16.
__global__ __launch_bounds__(256) void k_gemm2bn(
    const unsigned short* __restrict__ hp, int M,
    const unsigned short* __restrict__ Wb, int nslab,
    const float* __restrict__ ss,
    unsigned short* __restrict__ outLinB, unsigned short* __restrict__ outSelf) {
  __shared__ float sss[128];
  if (threadIdx.x < 128) sss[threadIdx.x] = ss[threadIdx.x];
  __syncthreads();
  int m0 = blockIdx.x * 64;
  int wid = threadIdx.x >> 6;
  int lane = threadIdx.x & 63;
  int mrow = m0 + wid * 16 + (lane & 15);
  int mload = (mrow < M) ? mrow : (M - 1);
  int cb = 8 * (lane >> 4);
  const unsigned short* arow = hp + (size_t)mload * 64 + cb;
  ushort4 u0 = *(const ushort4*)(arow);
  ushort4 u1 = *(const ushort4*)(arow + 4);
  ushort4 u2 = *(const ushort4*)(arow + 32);
  ushort4 u3 = *(const ushort4*)(arow + 36);
  bf16x8 a0, a1;
  #pragma unroll
  for (int j = 0; j < 4; j++) {
    unsigned short uu0 = (&u0.x)[j], uu1 = (&u1.x)[j], uu2 = (&u2.x)[j], uu3 = (&u3.x)[j];
    a0[j]     = (short)f2bf(fmaxf(fmaf(bf2f(uu0), sss[cb + j],      sss[64 + cb + j]), 0.f));
    a0[j + 4] = (short)f2bf(fmaxf(fmaf(bf2f(uu1), sss[cb + 4 + j],  sss[64 + cb + 4 + j]), 0.f));
    a1[j]     = (short)f2bf(fmaxf(fmaf(bf2f(uu2), sss[cb + 32 + j], sss[64 + cb + 32 + j]), 0.f));
    a1[j + 4] = (short)f2bf(fmaxf(fmaf(bf2f(uu3), sss[cb + 36 + j], sss[64 + cb + 36 + j]), 0.f));
  }
  int rbase = m0 + wid * 16 + ((lane >> 4) << 2);
  int cbase = lane & 15;
  for (int slab = 0; slab <= nslab; ++slab) {
    const unsigned short* wrow = Wb + ((size_t)slab * 64 + (lane & 15)) * 64 + 8 * (lane >> 4);
    unsigned short* op = (slab < nslab) ? (outLinB + (size_t)slab * M * 64) : outSelf;
    #pragma unroll
    for (int nt = 0; nt < 4; ++nt) {
      bf16x8 b0 = *(const bf16x8*)(wrow + nt * 16 * 64);
      bf16x8 b1 = *(const bf16x8*)(wrow + nt * 16 * 64 + 32);
      f32x4 c = {};
      c = __builtin_amdgcn_mfma_f32_16x16x32_bf16(a0, b0, c, 0, 0, 0);
      c = __builtin_amdgcn_mfma_f32_16x16x32_bf16(a1, b1, c, 0, 0, 0);
      int col = nt * 16 + cbase;
      #pragma unroll
      for (int rg = 0; rg < 4; ++rg) {
        int grow = rbase + rg;
        if (grow < M) op[(size_t)grow * 64 + col] = f2bf(c[rg]);
      }
    }
  }
}

// layer2 stats + SAVE pre-activation bf16 into the low half of each output
// row's own f32 slot in d_out (row s: bytes [s*256, s*256+128)).
__global__ __launch_bounds__(256) void k_gather2_statsave(
    const unsigned* __restrict__ descT, const unsigned* __restrict__ ep4,
    const unsigned short* __restrict__ z, const unsigned short* __restrict__ s2,
    float* __restrict__ part, unsigned short* __restrict__ pre, int N, int R) {
  int lane = threadIdx.x & 63;
  int wid = threadIdx.x >> 6;
  int l16 = lane & 15;
  int lg = lane >> 4;
  int c0 = l16 * 4;
  int grp = blockIdx.x * 16 + wid * 4 + lg;
  int ngrp = gridDim.x * 16;
  int NR = N * R;
  float lsum[4] = {0.f, 0.f, 0.f, 0.f}, lsq[4] = {0.f, 0.f, 0.f, 0.f};
  for (int s = grp; s < NR; s += ngrp) {
    unsigned r = (unsigned)s / (unsigned)N;
    int n = s - (int)r * N;
    unsigned desc = descT[s];
    int k = (int)(desc & 0xFFFFFu);
    int cnt = (int)(desc >> 20);
    int k1 = k + cnt;
    float a0 = 0.f, a1 = 0.f, a2 = 0.f, a3 = 0.f, d = 0.f;
    for (; k + 1 < k1; k += 2) {
      unsigned pA = ep4[k], pB = ep4[k + 1];
      ushort4 uA = *(const ushort4*)&z[(size_t)(pA & 0xFFFFu) * 64 + c0];
      ushort4 uB = *(const ushort4*)&z[(size_t)(pB & 0xFFFFu) * 64 + c0];
      float wA = bf2f((unsigned short)(pA >> 16));
      float wB = bf2f((unsigned short)(pB >> 16));
      d += wA + wB;
      a0 = fmaf(wA, bf2f(uA.x), a0); a1 = fmaf(wA, bf2f(uA.y), a1);
      a2 = fmaf(wA, bf2f(uA.z), a2); a3 = fmaf(wA, bf2f(uA.w), a3);
      a0 = fmaf(wB, bf2f(uB.x), a0); a1 = fmaf(wB, bf2f(uB.y), a1);
      a2 = fmaf(wB, bf2f(uB.z), a2); a3 = fmaf(wB, bf2f(uB.w), a3);
    }
    if (k < k1) {
      unsigned p = ep4[k];
      float w = bf2f((unsigned short)(p >> 16));
      ushort4 u = *(const ushort4*)&z[(size_t)(p & 0xFFFFu) * 64 + c0];
      d += w;
      a0 = fmaf(w, bf2f(u.x), a0); a1 = fmaf(w, bf2f(u.y), a1);
      a2 = fmaf(w, bf2f(u.z), a2); a3 = fmaf(w, bf2f(u.w), a3);
    }
    if (d != 0.f) {
      float inv = 1.f / d;
      a0 *= inv; a1 *= inv; a2 *= inv; a3 *= inv;
    }
    ushort4 su = *(const ushort4*)&s2[(size_t)n * 64 + c0];
    float v0 = a0 + bf2f(su.x), v1 = a1 + bf2f(su.y);
    float v2 = a2 + bf2f(su.z), v3 = a3 + bf2f(su.w);
    ushort4 o; o.x = f2bf(v0); o.y = f2bf(v1); o.z = f2bf(v2); o.w = f2bf(v3);
    *(ushort4*)&pre[(size_t)s * 128 + c0] = o;   // low half of row s's f32 slot
    lsum[0] += v0; lsq[0] += v0 * v0;
    lsum[1] += v1; lsq[1] += v1 * v1;
    lsum[2] += v2; lsq[2] += v2 * v2;
    lsum[3] += v3; lsq[3] += v3 * v3;
  }
  __shared__ float sp[16][64], sq[16][64];
  int g = wid * 4 + lg;
  #pragma unroll
  for (int i = 0; i < 4; i++) { sp[g][c0 + i] = lsum[i]; sq[g][c0 + i] = lsq[i]; }
  __syncthreads();
  if (threadIdx.x < 64) {
    int j = threadIdx.x;
    float s = 0.f, q = 0.f;
    #pragma unroll
    for (int gg = 0; gg < 16; gg++) { s += sp[gg][j]; q += sq[gg][j]; }
    part[(size_t)blockIdx.x * 128 + j] = s;
    part[(size_t)blockIdx.x * 128 + 64 + j] = q;
  }
}

// streaming in-place expand: row s low-half bf16 -> BN+relu -> full f32 row.
__global__ __launch_bounds__(256) void k_bnrelu_inplace(
    float* __restrict__ out, const float* __restrict__ ss, int NR) {
  __shared__ float sss[128];
  if (threadIdx.x < 128) sss[threadIdx.x] = ss[threadIdx.x];
  __syncthreads();
  int l16 = threadIdx.x & 15;
  int c0 = l16 * 4;
  float sc0 = sss[c0], sc1 = sss[c0 + 1], sc2 = sss[c0 + 2], sc3 = sss[c0 + 3];
  float sh0 = sss[64 + c0], sh1 = sss[64 + c0 + 1], sh2 = sss[64 + c0 + 2], sh3 = sss[64 + c0 + 3];
  int row = blockIdx.x * 16 + (threadIdx.x >> 4);
  int stride = gridDim.x * 16;
  const unsigned short* pre = (const unsigned short*)out;
  for (int s = row; s < NR; s += stride) {
    ushort4 u = *(const ushort4*)&pre[(size_t)s * 128 + c0];
    float v0 = fmaxf(fmaf(bf2f(u.x), sc0, sh0), 0.f);
    float v1 = fmaxf(fmaf(bf2f(u.y), sc1, sh1), 0.f);
    float v2 = fmaxf(fmaf(bf2f(u.z), sc2, sh2), 0.f);
    float v3 = fmaxf(fmaf(bf2f(u.w), sc3, sh3), 0.f);
    *(float4*)&out[(size_t)s * 64 + c0] = make_float4(v0, v1, v2, v3);
  }
}

// stage-1 reduce: part[P][128] -> part2[RED_BLOCKS][128]
__global__ __launch_bounds__(256) void k_red1(const float* __restrict__ part,
                                              float* __restrict__ part2, int P) {
  int j = threadIdx.x & 127;
  int g = threadIdx.x >> 7;
  int rows = (P + RED_BLOCKS - 1) / RED_BLOCKS;
  int base = blockIdx.x * rows;
  float acc = 0.f;
  for (int i = g; i < rows; i += 2) {
    int idx = base + i;
    if (idx < P) acc += part[(size_t)idx * 128 + j];
  }
  __shared__ float red[2][128];
  red[g][j] = acc;
  __syncthreads();
  if (threadIdx.x < 128) part2[(size_t)blockIdx.x * 128 + j] = red[0][j] + red[1][j];
}

__global__ __launch_bounds__(1024) void k_bnstats(
    const float* __restrict__ part, int P, float M,
    const float* __restrict__ gamma, const float* __restrict__ beta,
    float* __restrict__ ss) {
  __shared__ float red[1024];
  int tid = threadIdx.x;
  int j = tid & 127;
  int g = tid >> 7;
  float acc = 0.f;
  for (int i = g; i < P; i += 8) acc += part[(size_t)i * 128 + j];
  red[tid] = acc;
  __syncthreads();
  if (tid < 128) {
    float s = 0.f;
    for (int gg = 0; gg < 8; gg++) s += red[gg * 128 + tid];
    red[tid] = s;
  }
  __syncthreads();
  if (tid < 64) {
    float s = red[tid], q = red[64 + tid];
    float mean = s / M;
    float var = q / M - mean * mean;
    float sc = gamma[tid] / sqrtf(var + 1e-5f);
    ss[tid] = sc;
    ss[64 + tid] = beta[tid] - mean * sc;
  }
}

extern "C" void kernel_launch(void* const* d_in, const int* in_sizes, int n_in,
                              void* d_out, int out_size, void* d_ws, size_t ws_size,
                              hipStream_t stream) {
  const float* x        = (const float*)d_in[0];
  const float* edge_w   = (const float*)d_in[1];
  const float* W_lin1   = (const float*)d_in[2];
  const float* W_self1  = (const float*)d_in[4];
  const float* gamma1   = (const float*)d_in[6];
  const float* beta1    = (const float*)d_in[7];
  const float* W_lin2   = (const float*)d_in[8];
  const float* W_self2  = (const float*)d_in[10];
  const float* gamma2   = (const float*)d_in[12];
  const float* beta2    = (const float*)d_in[13];
  const int* node_in    = (const int*)d_in[14];
  const int* node_out   = (const int*)d_in[15];
  const int* relation   = (const int*)d_in[16];

  int N = in_sizes[0] / 64;           // 50000
  int E = in_sizes[1];                // 800000
  int R = in_sizes[2] / (64 * 64);    // 8
  int NR = N * R;
  int NB = (NR + SCAN_CHUNK - 1) / SCAN_CHUNK;

  char* p = (char*)d_ws;
  auto alloc = [&](size_t bytes) { char* r = p; p += (bytes + 255) & ~(size_t)255; return r; };
  int* cnt      = (int*)alloc(4ull * NR);
  int* rowptr   = (int*)alloc(4ull * (NR + 1));
  unsigned* descT = (unsigned*)alloc(4ull * NR);
  int* tmp      = (int*)alloc(4ull * E);
  int* bsum     = (int*)alloc(4ull * NB);
  int* bpre     = (int*)alloc(4ull * NB);
  unsigned* ep4 = (unsigned*)alloc(4ull * E);
  unsigned short* wb1 = (unsigned short*)alloc(2ull * 64 * (R * 64 + 64));
  unsigned short* wb2 = (unsigned short*)alloc(2ull * 2 * 64 * 64);
  unsigned short* h_pre = (unsigned short*)alloc(2ull * N * 64);
  unsigned short* z     = (unsigned short*)alloc(2ull * N * 64);
  unsigned short* s2    = (unsigned short*)alloc(2ull * N * 64);
  float* part   = (float*)alloc(4ull * GATHER_GRID * 128);
  float* part2  = (float*)alloc(4ull * RED_BLOCKS * 128);
  float* ss1    = (float*)alloc(4ull * 128);
  float* ss2    = (float*)alloc(4ull * 128);

  // d_out scratch: updx [N][512] bf16 [0,51.2MB) + xb [N][64] bf16 [51.2,57.6MB)
  // — both dead before statsave writes pre rows into d_out.
  unsigned short* updx = (unsigned short*)d_out;
  unsigned short* xb   = updx + (size_t)N * 512;

  int mblocks = (N + 63) / 64;        // 782

  k_zeropack<<<ZERO_BLOCKS + PACK_BLOCKS, 256, 0, stream>>>(
      cnt, NR, R, W_lin1, W_self1, W_lin2, W_self2, wb1, wb2);
  k_countx<<<XB_BLOCKS + COUNT_BLOCKS, 256, 0, stream>>>(
      node_out, relation, cnt, tmp, E, R, (const float4*)x, (ushort4*)xb, N * 64 / 4);
  k_scan1<<<NB, 256, 0, stream>>>(cnt, bsum, NR);
  k_scan2<<<1, 64, 0, stream>>>(bsum, bpre, &rowptr[NR], NB);
  k_scan3<<<NB, 256, 0, stream>>>(cnt, bpre, rowptr, descT, NR, R, N);
  k_place<<<PLACE_BLOCKS, 256, 0, stream>>>(
      edge_w, node_out, node_in, relation, rowptr, tmp, ep4, E, R);

  // layer 1: gatherx (L2-resident reads, coalesced writes) -> K=576 GEMM + stats
  k_gatherx<<<GATHER_GRID, 256, 0, stream>>>(rowptr, ep4, xb, updx, N, R);
  k_gemm1b<<<mblocks, 256, 0, stream>>>(updx, xb, N, wb1, h_pre, part);
  k_red1<<<RED_BLOCKS, 256, 0, stream>>>(part, part2, mblocks);
  k_bnstats<<<1, 1024, 0, stream>>>(part2, RED_BLOCKS, (float)N, gamma1, beta1, ss1);

  // layer 2: gemm (bn+relu fused on A) -> statsave -> stats -> in-place bnrelu
  k_gemm2bn<<<mblocks, 256, 0, stream>>>(h_pre, N, wb2, 1, ss1, z, s2);
  k_gather2_statsave<<<GATHER_GRID, 256, 0, stream>>>(
      descT, ep4, z, s2, part, (unsigned short*)d_out, N, R);
  k_red1<<<RED_BLOCKS, 256, 0, stream>>>(part, part2, GATHER_GRID);
  k_bnstats<<<1, 1024, 0, stream>>>(part2, RED_BLOCKS, (float)N * R, gamma2, beta2, ss2);
  k_bnrelu_inplace<<<4096, 256, 0, stream>>>((float*)d_out, ss2, NR);
}

// Round 18
// 238.352 us; speedup vs baseline: 1.0771x; 1.0771x over previous
//
#include <hip/hip_runtime.h>

// relationalGraphStack — round 17: revert to R14 (239.4us record).
// R15 (atomic MLP) and R16 (gatherx/gemm1b) both regressed — count is
// RMW-throughput-bound and layer-1 must keep gemm1 fused under count.
// Only change vs R14: k_place at 2048 blocks (more scattered-store MLP).

#define GATHER_GRID 2048
#define SCAN_CHUNK 4096
#define RED_BLOCKS 64
#define ZERO_BLOCKS 256
#define PACK_BLOCKS 16
#define COUNT_BLOCKS 2048
#define PLACE_BLOCKS 2048

typedef short bf16x8 __attribute__((ext_vector_type(8)));
typedef float f32x4 __attribute__((ext_vector_type(4)));

static __device__ __forceinline__ float bf2f(unsigned short u) {
  return __uint_as_float(((unsigned)u) << 16);
}
static __device__ __forceinline__ unsigned short f2bf(float f) {
  unsigned u = __float_as_uint(f);
  u += 0x7FFFu + ((u >> 16) & 1u);  // round to nearest even
  return (unsigned short)(u >> 16);
}

// zero cnt + pack weights (9-slab wb1; wb2 = [Wlin2; Wself2]).
__global__ void k_zeropack(int* __restrict__ cnt, int NR, int R,
                           const float* __restrict__ Wlin1, const float* __restrict__ Wself1,
                           const float* __restrict__ Wlin2, const float* __restrict__ Wself2,
                           unsigned short* __restrict__ wb1, unsigned short* __restrict__ wb2) {
  if (blockIdx.x < ZERO_BLOCKS) {
    int i = blockIdx.x * 256 + threadIdx.x;
    int stride = ZERO_BLOCKS * 256;
    for (int k = i; k < NR; k += stride) cnt[k] = 0;
  } else {
    int i = (blockIdx.x - ZERO_BLOCKS) * 256 + threadIdx.x;
    int stride = PACK_BLOCKS * 256;
    int n1 = (R + 1) * 64 * 64;
    int n2 = 2 * 64 * 64;
    for (int k = i; k < n1 + n2; k += stride) {
      if (k < n1) {
        int r = k >> 6, d = k & 63;
        float v;
        if (r < R * 64) {
          int s = r >> 6, j = r & 63;
          v = Wlin1[j * (R * 64) + s * 64 + d];
        } else {
          v = Wself1[(r - R * 64) * 64 + d];
        }
        wb1[k] = f2bf(v);
      } else {
        int k2 = k - n1;
        int r = k2 >> 6, d = k2 & 63;
        float v = (r < 64) ? Wlin2[r * 64 + d] : Wself2[(r - 64) * 64 + d];
        wb2[k2] = f2bf(v);
      }
    }
  }
}

// blocks [0,mblocks): gemm1 -> y1 bf16 slabs + s1 bf16.  blocks [mblocks,...):
// count edges per segment + rank tmp[e].
__global__ __launch_bounds__(256) void k_countgemm(
    const int* __restrict__ node_out, const int* __restrict__ rel,
    int* __restrict__ cnt, int* __restrict__ tmp, int E, int R,
    const float* __restrict__ xf, int M, const unsigned short* __restrict__ Wb,
    unsigned short* __restrict__ outLinB, unsigned short* __restrict__ outSelf,
    int mblocks) {
  if ((int)blockIdx.x < mblocks) {
    int m0 = blockIdx.x * 64;
    int wid = threadIdx.x >> 6;
    int lane = threadIdx.x & 63;
    int mrow = m0 + wid * 16 + (lane & 15);
    int mload = (mrow < M) ? mrow : (M - 1);
    const float* arow = xf + (size_t)mload * 64 + 8 * (lane >> 4);
    float4 af0 = *(const float4*)(arow);
    float4 af1 = *(const float4*)(arow + 4);
    float4 af2 = *(const float4*)(arow + 32);
    float4 af3 = *(const float4*)(arow + 36);
    bf16x8 a0, a1;
    a0[0] = (short)f2bf(af0.x); a0[1] = (short)f2bf(af0.y);
    a0[2] = (short)f2bf(af0.z); a0[3] = (short)f2bf(af0.w);
    a0[4] = (short)f2bf(af1.x); a0[5] = (short)f2bf(af1.y);
    a0[6] = (short)f2bf(af1.z); a0[7] = (short)f2bf(af1.w);
    a1[0] = (short)f2bf(af2.x); a1[1] = (short)f2bf(af2.y);
    a1[2] = (short)f2bf(af2.z); a1[3] = (short)f2bf(af2.w);
    a1[4] = (short)f2bf(af3.x); a1[5] = (short)f2bf(af3.y);
    a1[6] = (short)f2bf(af3.z); a1[7] = (short)f2bf(af3.w);
    int rbase = m0 + wid * 16 + ((lane >> 4) << 2);
    int cbase = lane & 15;
    for (int slab = 0; slab <= R; ++slab) {
      const unsigned short* wrow = Wb + ((size_t)slab * 64 + (lane & 15)) * 64 + 8 * (lane >> 4);
      unsigned short* op = (slab < R) ? (outLinB + (size_t)slab * M * 64) : outSelf;
      #pragma unroll
      for (int nt = 0; nt < 4; ++nt) {
        bf16x8 b0 = *(const bf16x8*)(wrow + nt * 16 * 64);
        bf16x8 b1 = *(const bf16x8*)(wrow + nt * 16 * 64 + 32);
        f32x4 c = {};
        c = __builtin_amdgcn_mfma_f32_16x16x32_bf16(a0, b0, c, 0, 0, 0);
        c = __builtin_amdgcn_mfma_f32_16x16x32_bf16(a1, b1, c, 0, 0, 0);
        int col = nt * 16 + cbase;
        #pragma unroll
        for (int rg = 0; rg < 4; ++rg) {
          int grow = rbase + rg;
          if (grow < M) op[(size_t)grow * 64 + col] = f2bf(c[rg]);
        }
      }
    }
  } else {
    int i = ((int)blockIdx.x - mblocks) * 256 + threadIdx.x;
    int stride = COUNT_BLOCKS * 256;
    for (int e = i; e < E; e += stride) {
      int seg = node_out[e] * R + rel[e];
      tmp[e] = atomicAdd(&cnt[seg], 1);
    }
  }
}

__global__ __launch_bounds__(256) void k_scan1(const int* __restrict__ cnt,
                                               int* __restrict__ bsum, int NR) {
  __shared__ int red[256];
  int tid = threadIdx.x;
  int base = blockIdx.x * SCAN_CHUNK;
  int s = 0;
  for (int i = tid; i < SCAN_CHUNK; i += 256) {
    int idx = base + i;
    if (idx < NR) s += cnt[idx];
  }
  red[tid] = s;
  __syncthreads();
  for (int off = 128; off > 0; off >>= 1) {
    if (tid < off) red[tid] += red[tid + off];
    __syncthreads();
  }
  if (tid == 0) bsum[blockIdx.x] = red[0];
}

__global__ void k_scan2(const int* __restrict__ bsum, int* __restrict__ bpre,
                        int* __restrict__ rowptr_end, int NB) {
  int lane = threadIdx.x;
  int carry = 0;
  for (int base = 0; base < NB; base += 64) {
    int i = base + lane;
    int v = (i < NB) ? bsum[i] : 0;
    int incl = v;
    #pragma unroll
    for (int off = 1; off < 64; off <<= 1) {
      int u = __shfl_up(incl, off);
      if (lane >= off) incl += u;
    }
    if (i < NB) bpre[i] = carry + incl - v;
    carry += __shfl(incl, 63);
  }
  if (lane == 0) *rowptr_end = carry;
}

// rowptr (n-major) + descT (s-major: descT[r*N+n] = start | cnt<<20)
__global__ __launch_bounds__(256) void k_scan3(const int* __restrict__ cnt,
                                               const int* __restrict__ bpre,
                                               int* __restrict__ rowptr,
                                               unsigned* __restrict__ descT,
                                               int NR, int R, int Nn) {
  __shared__ int wtot[4];
  int tid = threadIdx.x, lane = tid & 63, wid = tid >> 6;
  int base = blockIdx.x * SCAN_CHUNK + tid * 16;
  int v[16];
  int t = 0;
  #pragma unroll
  for (int i = 0; i < 16; i++) {
    int idx = base + i;
    v[i] = (idx < NR) ? cnt[idx] : 0;
    t += v[i];
  }
  int incl = t;
  #pragma unroll
  for (int off = 1; off < 64; off <<= 1) {
    int u = __shfl_up(incl, off);
    if (lane >= off) incl += u;
  }
  if (lane == 63) wtot[wid] = incl;
  __syncthreads();
  int woff = 0;
  for (int w = 0; w < wid; w++) woff += wtot[w];
  int start = bpre[blockIdx.x] + woff + incl - t;
  #pragma unroll
  for (int i = 0; i < 16; i++) {
    int idx = base + i;
    if (idx < NR) {
      rowptr[idx] = start;
      int n = (int)((unsigned)idx / (unsigned)R);
      int r = idx - n * R;
      descT[(size_t)r * Nn + n] = (unsigned)start | ((unsigned)v[i] << 20);
    }
    start += v[i];
  }
}

// placement, no atomics, 4B payload: ep4[rowptr[seg]+tmp[e]] = src | bf16(raw w)<<16
__global__ void k_place(const float* __restrict__ w, const int* __restrict__ node_out,
                        const int* __restrict__ node_in, const int* __restrict__ rel,
                        const int* __restrict__ rowptr, const int* __restrict__ tmp,
                        unsigned* __restrict__ ep4, int E, int R) {
  int i = blockIdx.x * blockDim.x + threadIdx.x;
  int stride = gridDim.x * blockDim.x;
  for (int e = i; e < E; e += stride) {
    int seg = node_out[e] * R + rel[e];
    int pos = rowptr[seg] + tmp[e];
    ep4[pos] = (unsigned)node_in[e] | ((unsigned)f2bf(w[e]) << 16);
  }
}

// layer1 gather, slab-phased: each group owns <=2 nodes (register partials).
__global__ __launch_bounds__(256) void k_gather1(
    const unsigned* __restrict__ descT, const unsigned* __restrict__ ep4,
    const unsigned short* __restrict__ y1, const unsigned short* __restrict__ s1,
    unsigned short* __restrict__ h_pre, float* __restrict__ part, int N, int R) {
  int lane = threadIdx.x & 63;
  int wid = threadIdx.x >> 6;
  int l16 = lane & 15;
  int lg = lane >> 4;
  int c0 = l16 * 4;
  int grp = blockIdx.x * 16 + wid * 4 + lg;
  int ngrp = gridDim.x * 16;          // 32768
  float t[2][4] = {{0.f,0.f,0.f,0.f},{0.f,0.f,0.f,0.f}};
  for (int r = 0; r < R; r++) {
    const unsigned short* yb = y1 + (size_t)r * N * 64;
    const unsigned* dT = descT + (size_t)r * N;
    #pragma unroll
    for (int u = 0; u < 2; u++) {
      int n = grp + u * ngrp;
      if (n < N) {
        unsigned desc = dT[n];
        int k = (int)(desc & 0xFFFFFu);
        int cnt = (int)(desc >> 20);
        int k1 = k + cnt;
        if (k < k1) {
          float a0 = 0.f, a1 = 0.f, a2 = 0.f, a3 = 0.f, d = 0.f;
          for (; k + 1 < k1; k += 2) {
            unsigned pA = ep4[k], pB = ep4[k + 1];
            ushort4 uA = *(const ushort4*)&yb[(size_t)(pA & 0xFFFFu) * 64 + c0];
            ushort4 uB = *(const ushort4*)&yb[(size_t)(pB & 0xFFFFu) * 64 + c0];
            float wA = bf2f((unsigned short)(pA >> 16));
            float wB = bf2f((unsigned short)(pB >> 16));
            d += wA + wB;
            a0 = fmaf(wA, bf2f(uA.x), a0); a1 = fmaf(wA, bf2f(uA.y), a1);
            a2 = fmaf(wA, bf2f(uA.z), a2); a3 = fmaf(wA, bf2f(uA.w), a3);
            a0 = fmaf(wB, bf2f(uB.x), a0); a1 = fmaf(wB, bf2f(uB.y), a1);
            a2 = fmaf(wB, bf2f(uB.z), a2); a3 = fmaf(wB, bf2f(uB.w), a3);
          }
          if (k < k1) {
            unsigned p = ep4[k];
            float w = bf2f((unsigned short)(p >> 16));
            ushort4 uu = *(const ushort4*)&yb[(size_t)(p & 0xFFFFu) * 64 + c0];
            d += w;
            a0 = fmaf(w, bf2f(uu.x), a0); a1 = fmaf(w, bf2f(uu.y), a1);
            a2 = fmaf(w, bf2f(uu.z), a2); a3 = fmaf(w, bf2f(uu.w), a3);
          }
          if (d != 0.f) {
            float inv = 1.f / d;
            t[u][0] = fmaf(a0, inv, t[u][0]);
            t[u][1] = fmaf(a1, inv, t[u][1]);
            t[u][2] = fmaf(a2, inv, t[u][2]);
            t[u][3] = fmaf(a3, inv, t[u][3]);
          }
        }
      }
    }
  }
  float lsum[4] = {0.f, 0.f, 0.f, 0.f}, lsq[4] = {0.f, 0.f, 0.f, 0.f};
  #pragma unroll
  for (int u = 0; u < 2; u++) {
    int n = grp + u * ngrp;
    if (n < N) {
      ushort4 su = *(const ushort4*)&s1[(size_t)n * 64 + c0];
      float v0 = t[u][0] + bf2f(su.x), v1 = t[u][1] + bf2f(su.y);
      float v2 = t[u][2] + bf2f(su.z), v3 = t[u][3] + bf2f(su.w);
      ushort4 o; o.x = f2bf(v0); o.y = f2bf(v1); o.z = f2bf(v2); o.w = f2bf(v3);
      *(ushort4*)&h_pre[(size_t)n * 64 + c0] = o;
      lsum[0] += v0; lsq[0] += v0 * v0;
      lsum[1] += v1; lsq[1] += v1 * v1;
      lsum[2] += v2; lsq[2] += v2 * v2;
      lsum[3] += v3; lsq[3] += v3 * v3;
    }
  }
  __shared__ float sp[16][64], sq[16][64];
  int g = wid * 4 + lg;
  #pragma unroll
  for (int i = 0; i < 4; i++) { sp[g][c0 + i] = lsum[i]; sq[g][c0 + i] = lsq[i]; }
  __syncthreads();
  if (threadIdx.x < 64) {
    int j = threadIdx.x;
    float s = 0.f, q = 0.f;
    #pragma unroll
    for (int gg = 0; gg < 16; gg++) { s += sp[gg][j]; q += sq[gg][j]; }
    part[(size_t)blockIdx.x * 128 + j] = s;
    part[(size_t)blockIdx.x * 128 + 64 + j] = q;
  }
}

// gemm2 with fused bn+relu on A (h_pre) using ss1 -> z bf16, s2 bf16.
__global__ __launch_bounds__(256) void k_gemm2bn(
    const unsigned short* __restrict__ hp, int M,
    const unsigned short* __restrict__ Wb, int nslab,
    const float* __restrict__ ss,
    unsigned short* __restrict__ outLinB, unsigned short* __restrict__ outSelf) {
  __shared__ float sss[128];
  if (threadIdx.x < 128) sss[threadIdx.x] = ss[threadIdx.x];
  __syncthreads();
  int m0 = blockIdx.x * 64;
  int wid = threadIdx.x >> 6;
  int lane = threadIdx.x & 63;
  int mrow = m0 + wid * 16 + (lane & 15);
  int mload = (mrow < M) ? mrow : (M - 1);
  int cb = 8 * (lane >> 4);
  const unsigned short* arow = hp + (size_t)mload * 64 + cb;
  ushort4 u0 = *(const ushort4*)(arow);
  ushort4 u1 = *(const ushort4*)(arow + 4);
  ushort4 u2 = *(const ushort4*)(arow + 32);
  ushort4 u3 = *(const ushort4*)(arow + 36);
  bf16x8 a0, a1;
  #pragma unroll
  for (int j = 0; j < 4; j++) {
    unsigned short uu0 = (&u0.x)[j], uu1 = (&u1.x)[j], uu2 = (&u2.x)[j], uu3 = (&u3.x)[j];
    a0[j]     = (short)f2bf(fmaxf(fmaf(bf2f(uu0), sss[cb + j],      sss[64 + cb + j]), 0.f));
    a0[j + 4] = (short)f2bf(fmaxf(fmaf(bf2f(uu1), sss[cb + 4 + j],  sss[64 + cb + 4 + j]), 0.f));
    a1[j]     = (short)f2bf(fmaxf(fmaf(bf2f(uu2), sss[cb + 32 + j], sss[64 + cb + 32 + j]), 0.f));
    a1[j + 4] = (short)f2bf(fmaxf(fmaf(bf2f(uu3), sss[cb + 36 + j], sss[64 + cb + 36 + j]), 0.f));
  }
  int rbase = m0 + wid * 16 + ((lane >> 4) << 2);
  int cbase = lane & 15;
  for (int slab = 0; slab <= nslab; ++slab) {
    const unsigned short* wrow = Wb + ((size_t)slab * 64 + (lane & 15)) * 64 + 8 * (lane >> 4);
    unsigned short* op = (slab < nslab) ? (outLinB + (size_t)slab * M * 64) : outSelf;
    #pragma unroll
    for (int nt = 0; nt < 4; ++nt) {
      bf16x8 b0 = *(const bf16x8*)(wrow + nt * 16 * 64);
      bf16x8 b1 = *(const bf16x8*)(wrow + nt * 16 * 64 + 32);
      f32x4 c = {};
      c = __builtin_amdgcn_mfma_f32_16x16x32_bf16(a0, b0, c, 0, 0, 0);
      c = __builtin_amdgcn_mfma_f32_16x16x32_bf16(a1, b1, c, 0, 0, 0);
      int col = nt * 16 + cbase;
      #pragma unroll
      for (int rg = 0; rg < 4; ++rg) {
        int grow = rbase + rg;
        if (grow < M) op[(size_t)grow * 64 + col] = f2bf(c[rg]);
      }
    }
  }
}

// layer2 stats + SAVE pre-activation bf16 into the low half of each output
// row's own f32 slot in d_out (row s: bytes [s*256, s*256+128)).
__global__ __launch_bounds__(256) void k_gather2_statsave(
    const unsigned* __restrict__ descT, const unsigned* __restrict__ ep4,
    const unsigned short* __restrict__ z, const unsigned short* __restrict__ s2,
    float* __restrict__ part, unsigned short* __restrict__ pre, int N, int R) {
  int lane = threadIdx.x & 63;
  int wid = threadIdx.x >> 6;
  int l16 = lane & 15;
  int lg = lane >> 4;
  int c0 = l16 * 4;
  int grp = blockIdx.x * 16 + wid * 4 + lg;
  int ngrp = gridDim.x * 16;
  int NR = N * R;
  float lsum[4] = {0.f, 0.f, 0.f, 0.f}, lsq[4] = {0.f, 0.f, 0.f, 0.f};
  for (int s = grp; s < NR; s += ngrp) {
    unsigned r = (unsigned)s / (unsigned)N;
    int n = s - (int)r * N;
    unsigned desc = descT[s];
    int k = (int)(desc & 0xFFFFFu);
    int cnt = (int)(desc >> 20);
    int k1 = k + cnt;
    float a0 = 0.f, a1 = 0.f, a2 = 0.f, a3 = 0.f, d = 0.f;
    for (; k + 1 < k1; k += 2) {
      unsigned pA = ep4[k], pB = ep4[k + 1];
      ushort4 uA = *(const ushort4*)&z[(size_t)(pA & 0xFFFFu) * 64 + c0];
      ushort4 uB = *(const ushort4*)&z[(size_t)(pB & 0xFFFFu) * 64 + c0];
      float wA = bf2f((unsigned short)(pA >> 16));
      float wB = bf2f((unsigned short)(pB >> 16));
      d += wA + wB;
      a0 = fmaf(wA, bf2f(uA.x), a0); a1 = fmaf(wA, bf2f(uA.y), a1);
      a2 = fmaf(wA, bf2f(uA.z), a2); a3 = fmaf(wA, bf2f(uA.w), a3);
      a0 = fmaf(wB, bf2f(uB.x), a0); a1 = fmaf(wB, bf2f(uB.y), a1);
      a2 = fmaf(wB, bf2f(uB.z), a2); a3 = fmaf(wB, bf2f(uB.w), a3);
    }
    if (k < k1) {
      unsigned p = ep4[k];
      float w = bf2f((unsigned short)(p >> 16));
      ushort4 u = *(const ushort4*)&z[(size_t)(p & 0xFFFFu) * 64 + c0];
      d += w;
      a0 = fmaf(w, bf2f(u.x), a0); a1 = fmaf(w, bf2f(u.y), a1);
      a2 = fmaf(w, bf2f(u.z), a2); a3 = fmaf(w, bf2f(u.w), a3);
    }
    if (d != 0.f) {
      float inv = 1.f / d;
      a0 *= inv; a1 *= inv; a2 *= inv; a3 *= inv;
    }
    ushort4 su = *(const ushort4*)&s2[(size_t)n * 64 + c0];
    float v0 = a0 + bf2f(su.x), v1 = a1 + bf2f(su.y);
    float v2 = a2 + bf2f(su.z), v3 = a3 + bf2f(su.w);
    ushort4 o; o.x = f2bf(v0); o.y = f2bf(v1); o.z = f2bf(v2); o.w = f2bf(v3);
    *(ushort4*)&pre[(size_t)s * 128 + c0] = o;   // low half of row s's f32 slot
    lsum[0] += v0; lsq[0] += v0 * v0;
    lsum[1] += v1; lsq[1] += v1 * v1;
    lsum[2] += v2; lsq[2] += v2 * v2;
    lsum[3] += v3; lsq[3] += v3 * v3;
  }
  __shared__ float sp[16][64], sq[16][64];
  int g = wid * 4 + lg;
  #pragma unroll
  for (int i = 0; i < 4; i++) { sp[g][c0 + i] = lsum[i]; sq[g][c0 + i] = lsq[i]; }
  __syncthreads();
  if (threadIdx.x < 64) {
    int j = threadIdx.x;
    float s = 0.f, q = 0.f;
    #pragma unroll
    for (int gg = 0; gg < 16; gg++) { s += sp[gg][j]; q += sq[gg][j]; }
    part[(size_t)blockIdx.x * 128 + j] = s;
    part[(size_t)blockIdx.x * 128 + 64 + j] = q;
  }
}

// streaming in-place expand: row s low-half bf16 -> BN+relu -> full f32 row.
__global__ __launch_bounds__(256) void k_bnrelu_inplace(
    float* __restrict__ out, const float* __restrict__ ss, int NR) {
  __shared__ float sss[128];
  if (threadIdx.x < 128) sss[threadIdx.x] = ss[threadIdx.x];
  __syncthreads();
  int l16 = threadIdx.x & 15;
  int c0 = l16 * 4;
  float sc0 = sss[c0], sc1 = sss[c0 + 1], sc2 = sss[c0 + 2], sc3 = sss[c0 + 3];
  float sh0 = sss[64 + c0], sh1 = sss[64 + c0 + 1], sh2 = sss[64 + c0 + 2], sh3 = sss[64 + c0 + 3];
  int row = blockIdx.x * 16 + (threadIdx.x >> 4);
  int stride = gridDim.x * 16;
  const unsigned short* pre = (const unsigned short*)out;
  for (int s = row; s < NR; s += stride) {
    ushort4 u = *(const ushort4*)&pre[(size_t)s * 128 + c0];
    float v0 = fmaxf(fmaf(bf2f(u.x), sc0, sh0), 0.f);
    float v1 = fmaxf(fmaf(bf2f(u.y), sc1, sh1), 0.f);
    float v2 = fmaxf(fmaf(bf2f(u.z), sc2, sh2), 0.f);
    float v3 = fmaxf(fmaf(bf2f(u.w), sc3, sh3), 0.f);
    *(float4*)&out[(size_t)s * 64 + c0] = make_float4(v0, v1, v2, v3);
  }
}

// stage-1 reduce: part[P][128] -> part2[RED_BLOCKS][128]
__global__ __launch_bounds__(256) void k_red1(const float* __restrict__ part,
                                              float* __restrict__ part2, int P) {
  int j = threadIdx.x & 127;
  int g = threadIdx.x >> 7;
  int rows = (P + RED_BLOCKS - 1) / RED_BLOCKS;
  int base = blockIdx.x * rows;
  float acc = 0.f;
  for (int i = g; i < rows; i += 2) {
    int idx = base + i;
    if (idx < P) acc += part[(size_t)idx * 128 + j];
  }
  __shared__ float red[2][128];
  red[g][j] = acc;
  __syncthreads();
  if (threadIdx.x < 128) part2[(size_t)blockIdx.x * 128 + j] = red[0][j] + red[1][j];
}

__global__ __launch_bounds__(1024) void k_bnstats(
    const float* __restrict__ part, int P, float M,
    const float* __restrict__ gamma, const float* __restrict__ beta,
    float* __restrict__ ss) {
  __shared__ float red[1024];
  int tid = threadIdx.x;
  int j = tid & 127;
  int g = tid >> 7;
  float acc = 0.f;
  for (int i = g; i < P; i += 8) acc += part[(size_t)i * 128 + j];
  red[tid] = acc;
  __syncthreads();
  if (tid < 128) {
    float s = 0.f;
    for (int gg = 0; gg < 8; gg++) s += red[gg * 128 + tid];
    red[tid] = s;
  }
  __syncthreads();
  if (tid < 64) {
    float s = red[tid], q = red[64 + tid];
    float mean = s / M;
    float var = q / M - mean * mean;
    float sc = gamma[tid] / sqrtf(var + 1e-5f);
    ss[tid] = sc;
    ss[64 + tid] = beta[tid] - mean * sc;
  }
}

extern "C" void kernel_launch(void* const* d_in, const int* in_sizes, int n_in,
                              void* d_out, int out_size, void* d_ws, size_t ws_size,
                              hipStream_t stream) {
  const float* x        = (const float*)d_in[0];
  const float* edge_w   = (const float*)d_in[1];
  const float* W_lin1   = (const float*)d_in[2];
  const float* W_self1  = (const float*)d_in[4];
  const float* gamma1   = (const float*)d_in[6];
  const float* beta1    = (const float*)d_in[7];
  const float* W_lin2   = (const float*)d_in[8];
  const float* W_self2  = (const float*)d_in[10];
  const float* gamma2   = (const float*)d_in[12];
  const float* beta2    = (const float*)d_in[13];
  const int* node_in    = (const int*)d_in[14];
  const int* node_out   = (const int*)d_in[15];
  const int* relation   = (const int*)d_in[16];

  int N = in_sizes[0] / 64;           // 50000
  int E = in_sizes[1];                // 800000
  int R = in_sizes[2] / (64 * 64);    // 8
  int NR = N * R;
  int NB = (NR + SCAN_CHUNK - 1) / SCAN_CHUNK;

  char* p = (char*)d_ws;
  auto alloc = [&](size_t bytes) { char* r = p; p += (bytes + 255) & ~(size_t)255; return r; };
  int* cnt      = (int*)alloc(4ull * NR);
  int* rowptr   = (int*)alloc(4ull * (NR + 1));
  unsigned* descT = (unsigned*)alloc(4ull * NR);
  int* tmp      = (int*)alloc(4ull * E);
  int* bsum     = (int*)alloc(4ull * NB);
  int* bpre     = (int*)alloc(4ull * NB);
  unsigned* ep4 = (unsigned*)alloc(4ull * E);
  unsigned short* wb1 = (unsigned short*)alloc(2ull * (R + 1) * 64 * 64);
  unsigned short* wb2 = (unsigned short*)alloc(2ull * 2 * 64 * 64);
  unsigned short* s1    = (unsigned short*)alloc(2ull * N * 64);
  unsigned short* h_pre = (unsigned short*)alloc(2ull * N * 64);
  unsigned short* z     = (unsigned short*)alloc(2ull * N * 64);
  unsigned short* s2    = (unsigned short*)alloc(2ull * N * 64);
  float* part   = (float*)alloc(4ull * GATHER_GRID * 128);
  float* part2  = (float*)alloc(4ull * RED_BLOCKS * 128);
  float* ss1    = (float*)alloc(4ull * 128);
  float* ss2    = (float*)alloc(4ull * 128);

  // d_out scratch: y1 bf16 [0, 51.2MB) — dead before statsave writes pre rows.
  unsigned short* y1 = (unsigned short*)d_out;

  int mblocks = (N + 63) / 64;

  k_zeropack<<<ZERO_BLOCKS + PACK_BLOCKS, 256, 0, stream>>>(
      cnt, NR, R, W_lin1, W_self1, W_lin2, W_self2, wb1, wb2);
  k_countgemm<<<mblocks + COUNT_BLOCKS, 256, 0, stream>>>(
      node_out, relation, cnt, tmp, E, R, x, N, wb1, y1, s1, mblocks);
  k_scan1<<<NB, 256, 0, stream>>>(cnt, bsum, NR);
  k_scan2<<<1, 64, 0, stream>>>(bsum, bpre, &rowptr[NR], NB);
  k_scan3<<<NB, 256, 0, stream>>>(cnt, bpre, rowptr, descT, NR, R, N);
  k_place<<<PLACE_BLOCKS, 256, 0, stream>>>(
      edge_w, node_out, node_in, relation, rowptr, tmp, ep4, E, R);

  // layer 1 gather (slab-phased, +stats, inline-d norm)
  k_gather1<<<GATHER_GRID, 256, 0, stream>>>(descT, ep4, y1, s1, h_pre, part, N, R);
  k_red1<<<RED_BLOCKS, 256, 0, stream>>>(part, part2, GATHER_GRID);
  k_bnstats<<<1, 1024, 0, stream>>>(part2, RED_BLOCKS, (float)N, gamma1, beta1, ss1);

  // layer 2: gemm (bn+relu fused on A) -> statsave -> stats -> in-place bnrelu
  k_gemm2bn<<<mblocks, 256, 0, stream>>>(h_pre, N, wb2, 1, ss1, z, s2);
  k_gather2_statsave<<<GATHER_GRID, 256, 0, stream>>>(
      descT, ep4, z, s2, part, (unsigned short*)d_out, N, R);
  k_red1<<<RED_BLOCKS, 256, 0, stream>>>(part, part2, GATHER_GRID);
  k_bnstats<<<1, 1024, 0, stream>>>(part2, RED_BLOCKS, (float)N * R, gamma2, beta2, ss2);
  k_bnrelu_inplace<<<4096, 256, 0, stream>>>((float*)d_out, ss2, NR);
}